// Round 2
// baseline (87.654 us; speedup 1.0000x reference)
//
#include <hip/hip_runtime.h>
#include <hip/hip_bf16.h>

#define B_SZ   1024
#define IN_F   256
#define OUT_F  256
#define NB     9            // 8 spline bases + 1 silu/base term
#define KTOT   (IN_F * NB)  // 2304
#define NGRID  12           // GRID_SIZE + 2K + 1

typedef __attribute__((ext_vector_type(8))) short bf16x8;
typedef __attribute__((ext_vector_type(4))) float f32x4;

// ---------------------------------------------------------------------------
// Kernel 1: per-(b,i) element -> 8 cubic B-spline bases + silu, packed into
// Phi[b][k] with k = n*256 + i  (bf16). Coalesced 2B stores per n-plane.
// ---------------------------------------------------------------------------
__global__ __launch_bounds__(256) void kan_features(
    const float* __restrict__ x,
    const float* __restrict__ grid,
    __hip_bfloat16* __restrict__ phi) {
  int idx = blockIdx.x * 256 + threadIdx.x;   // 0 .. B*IN_F-1

  float g[NGRID];
#pragma unroll
  for (int j = 0; j < NGRID; ++j) g[j] = grid[j];

  float xv = x[idx];

  // order-0 indicators
  float bas[NGRID - 1];
#pragma unroll
  for (int j = 0; j < NGRID - 1; ++j)
    bas[j] = (xv >= g[j] && xv < g[j + 1]) ? 1.0f : 0.0f;

  // de Boor recursion, p = 1..3 (ascending j keeps bas[j+1] = old value)
#pragma unroll
  for (int p = 1; p <= 3; ++p) {
    int n = NGRID - 1 - p;
#pragma unroll
    for (int j = 0; j < n; ++j) {
      float ld = g[p + j] - g[j];
      if (ld < 1e-8f) ld = 1e-8f;
      float rd = g[p + 1 + j] - g[j + 1];
      if (rd < 1e-8f) rd = 1e-8f;
      bas[j] = (xv - g[j]) * __builtin_amdgcn_rcpf(ld) * bas[j] +
               (g[p + 1 + j] - xv) * __builtin_amdgcn_rcpf(rd) * bas[j + 1];
    }
  }
  // right-edge fixup: bases[:, -1] += (x >= grid[-k-1])
  bas[7] += (xv >= g[NGRID - 4]) ? 1.0f : 0.0f;

  float sil = xv / (1.0f + __expf(-xv));   // silu in f32

  int b = idx >> 8;
  int i = idx & 255;
  __hip_bfloat16* dst = phi + b * KTOT + i;
#pragma unroll
  for (int n = 0; n < 8; ++n) dst[n * IN_F] = __float2bfloat16(bas[n]);
  dst[8 * IN_F] = __float2bfloat16(sil);
}

// ---------------------------------------------------------------------------
// Kernel 2: W[o][k] with k = n*256 + i:  n<8 -> sw[o,i]*coeff[o,i,n],
// n==8 -> bw[o,i]  (bf16)
// ---------------------------------------------------------------------------
__global__ __launch_bounds__(256) void kan_weights(
    const float* __restrict__ coeff,
    const float* __restrict__ bw,
    const float* __restrict__ sw,
    __hip_bfloat16* __restrict__ W) {
  int idx = blockIdx.x * 256 + threadIdx.x;   // o*256 + i, 0..65535
  int o = idx >> 8;
  int i = idx & 255;
  float s = sw[idx];
  const float* c = coeff + (size_t)idx * 8;   // contiguous 32B
  __hip_bfloat16* dst = W + o * KTOT + i;
#pragma unroll
  for (int n = 0; n < 8; ++n)
    dst[n * IN_F] = __float2bfloat16(s * c[n]);
  dst[8 * IN_F] = __float2bfloat16(bw[idx]);
}

// ---------------------------------------------------------------------------
// Kernel 3: C[b][o] = dot(Phi[b][:], W[o][:]) over K=2304, NT GEMM via
// mfma_f32_16x16x32_bf16. One wave per 16x16 tile; frags straight from L2.
// A/B frag: lane holds row (lane&15), k = (lane>>4)*8 + j  [m89/m92 layout]
// C/D: col = lane&15, row = (lane>>4)*4 + reg               [m89 verified]
// ---------------------------------------------------------------------------
__global__ __launch_bounds__(256) void kan_gemm(
    const __hip_bfloat16* __restrict__ phi,
    const __hip_bfloat16* __restrict__ W,
    float* __restrict__ out) {
  int wave = ((blockIdx.x * 256) + threadIdx.x) >> 6;  // 0..1023
  int lane = threadIdx.x & 63;
  int to = wave & 15;        // o-tile: 16 tiles of 16
  int tb = wave >> 4;        // b-tile: 64 tiles of 16
  int m = lane & 15;
  int q = lane >> 4;

  const short* ap = (const short*)(phi + (tb * 16 + m) * KTOT + q * 8);
  const short* bp = (const short*)(W + (to * 16 + m) * KTOT + q * 8);

  f32x4 acc = {0.f, 0.f, 0.f, 0.f};
#pragma unroll 8
  for (int k = 0; k < KTOT; k += 32) {
    bf16x8 a = *(const bf16x8*)(ap + k);
    bf16x8 b = *(const bf16x8*)(bp + k);
    acc = __builtin_amdgcn_mfma_f32_16x16x32_bf16(a, b, acc, 0, 0, 0);
  }

  int row = tb * 16 + q * 4;
  int col = to * 16 + m;
#pragma unroll
  for (int r = 0; r < 4; ++r)
    out[(row + r) * OUT_F + col] = acc[r];
}

// ---------------------------------------------------------------------------
extern "C" void kernel_launch(void* const* d_in, const int* in_sizes, int n_in,
                              void* d_out, int out_size, void* d_ws, size_t ws_size,
                              hipStream_t stream) {
  const float* x     = (const float*)d_in[0];
  const float* grid  = (const float*)d_in[1];
  const float* coeff = (const float*)d_in[2];
  const float* bw    = (const float*)d_in[3];
  const float* sw    = (const float*)d_in[4];
  float* out = (float*)d_out;

  __hip_bfloat16* phi = (__hip_bfloat16*)d_ws;            // 1024*2304 bf16 = 4.5 MiB
  __hip_bfloat16* W   = phi + (size_t)B_SZ * KTOT;        // 256*2304 bf16 = 1.125 MiB

  kan_features<<<(B_SZ * IN_F) / 256, 256, 0, stream>>>(x, grid, phi);
  kan_weights<<<(OUT_F * IN_F) / 256, 256, 0, stream>>>(coeff, bw, sw, W);
  kan_gemm<<<(B_SZ / 16) * (OUT_F / 16) / 4, 256, 0, stream>>>(phi, W, out);
}

// Round 3
// 76.750 us; speedup vs baseline: 1.1421x; 1.1421x over previous
//
#include <hip/hip_runtime.h>
#include <hip/hip_bf16.h>

#define B_SZ   1024
#define IN_F   256
#define OUT_F  256
#define NB     9            // 8 spline bases + 1 silu/base term
#define KTOT   (IN_F * NB)  // 2304
#define NGRID  12           // GRID_SIZE + 2K + 1

typedef __attribute__((ext_vector_type(8))) short  bf16x8;
typedef __attribute__((ext_vector_type(16))) float f32x16;

// ---------------------------------------------------------------------------
// Prep kernel (fused): blocks [0,1024) build Phi, blocks [1024,1280) build W.
// Phi[b][k], k = n*256 + i : 8 cubic B-spline bases (+edge fixup) and silu(x).
// W[o][k],  k = n*256 + i : n<8 -> sw*coeff ; n==8 -> bw.   Both bf16.
// ---------------------------------------------------------------------------
__global__ __launch_bounds__(256) void kan_prep(
    const float* __restrict__ x,
    const float* __restrict__ grid,
    const float* __restrict__ coeff,
    const float* __restrict__ bw,
    const float* __restrict__ sw,
    __hip_bfloat16* __restrict__ phi,
    __hip_bfloat16* __restrict__ W) {
  if (blockIdx.x < (B_SZ * IN_F) / 256) {
    // ---- features ----
    int idx = blockIdx.x * 256 + threadIdx.x;   // 0 .. B*IN_F-1
    float g[NGRID];
#pragma unroll
    for (int j = 0; j < NGRID; ++j) g[j] = grid[j];
    float xv = x[idx];

    float bas[NGRID - 1];
#pragma unroll
    for (int j = 0; j < NGRID - 1; ++j)
      bas[j] = (xv >= g[j] && xv < g[j + 1]) ? 1.0f : 0.0f;

#pragma unroll
    for (int p = 1; p <= 3; ++p) {
      int n = NGRID - 1 - p;
#pragma unroll
      for (int j = 0; j < n; ++j) {
        float ld = g[p + j] - g[j];
        if (ld < 1e-8f) ld = 1e-8f;
        float rd = g[p + 1 + j] - g[j + 1];
        if (rd < 1e-8f) rd = 1e-8f;
        bas[j] = (xv - g[j]) * __builtin_amdgcn_rcpf(ld) * bas[j] +
                 (g[p + 1 + j] - xv) * __builtin_amdgcn_rcpf(rd) * bas[j + 1];
      }
    }
    bas[7] += (xv >= g[NGRID - 4]) ? 1.0f : 0.0f;
    float sil = xv / (1.0f + __expf(-xv));

    int b = idx >> 8;
    int i = idx & 255;
    __hip_bfloat16* dst = phi + b * KTOT + i;
#pragma unroll
    for (int n = 0; n < 8; ++n) dst[n * IN_F] = __float2bfloat16(bas[n]);
    dst[8 * IN_F] = __float2bfloat16(sil);
  } else {
    // ---- weights ----
    int idx = (blockIdx.x - (B_SZ * IN_F) / 256) * 256 + threadIdx.x;  // 0..65535
    int o = idx >> 8;
    int i = idx & 255;
    float s = sw[idx];
    const float* c = coeff + (size_t)idx * 8;
    __hip_bfloat16* dst = W + o * KTOT + i;
#pragma unroll
    for (int n = 0; n < 8; ++n)
      dst[n * IN_F] = __float2bfloat16(s * c[n]);
    dst[8 * IN_F] = __float2bfloat16(bw[idx]);
  }
}

// ---------------------------------------------------------------------------
// GEMM: C[1024x256] = Phi · W^T, K=2304, bf16 in / f32 out.
// 256 blocks × 512 threads. Each block owns one 32x32 C-tile; its 8 waves
// split K (288 each, 18 × mfma_f32_32x32x16_bf16), then LDS tree-reduce.
// A/B frag (32x32x16): lane holds row (lane&31), k = (lane>>5)*8 + j.
// C/D (32x32): col = lane&31, row = (reg&3) + 8*(reg>>2) + 4*(lane>>5). [m74/m101]
// Block mapping: bm fast index -> each XCD (blockIdx%8 r-r) touches only
// 4 phi strips (590 KB) + W (1.1 MB) => fully L2-resident per XCD.
// ---------------------------------------------------------------------------
#define KSEG (KTOT / 8)   // 288 per wave

__global__ __launch_bounds__(512) void kan_gemm(
    const __hip_bfloat16* __restrict__ phi,
    const __hip_bfloat16* __restrict__ W,
    float* __restrict__ out) {
  __shared__ float partial[8][32 * 32];   // 32 KB

  int tid  = threadIdx.x;
  int wave = tid >> 6;          // 0..7
  int lane = tid & 63;
  int bm = (blockIdx.x & 31) * 32;   // 32 b-tiles (fast index)
  int bn = (blockIdx.x >> 5) * 32;   // 8 o-tiles
  int r = lane & 31;
  int h = lane >> 5;            // half-wave

  const short* ap = (const short*)(phi + (size_t)(bm + r) * KTOT) + wave * KSEG + h * 8;
  const short* bp = (const short*)(W   + (size_t)(bn + r) * KTOT) + wave * KSEG + h * 8;

  f32x16 acc;
#pragma unroll
  for (int g = 0; g < 16; ++g) acc[g] = 0.0f;

#pragma unroll 6
  for (int k = 0; k < KSEG; k += 16) {
    bf16x8 a = *(const bf16x8*)(ap + k);
    bf16x8 b = *(const bf16x8*)(bp + k);
    acc = __builtin_amdgcn_mfma_f32_32x32x16_bf16(a, b, acc, 0, 0, 0);
  }

  float* pw = &partial[wave][0];
#pragma unroll
  for (int g = 0; g < 16; ++g) {
    int row = (g & 3) + 8 * (g >> 2) + 4 * h;
    pw[row * 32 + r] = acc[g];   // lanes 0..31 -> banks 0..31: conflict-free
  }
  __syncthreads();

  // reduce 8 partials; 512 threads × 2 consecutive elements (2-way LDS = free)
  int e0 = tid * 2;
  float s0 = 0.0f, s1 = 0.0f;
#pragma unroll
  for (int w = 0; w < 8; ++w) {
    s0 += partial[w][e0];
    s1 += partial[w][e0 + 1];
  }
  int row = e0 >> 5, col = e0 & 31;
  float2 v = make_float2(s0, s1);
  *(float2*)&out[(size_t)(bm + row) * OUT_F + bn + col] = v;
}

// ---------------------------------------------------------------------------
extern "C" void kernel_launch(void* const* d_in, const int* in_sizes, int n_in,
                              void* d_out, int out_size, void* d_ws, size_t ws_size,
                              hipStream_t stream) {
  const float* x     = (const float*)d_in[0];
  const float* grid  = (const float*)d_in[1];
  const float* coeff = (const float*)d_in[2];
  const float* bw    = (const float*)d_in[3];
  const float* sw    = (const float*)d_in[4];
  float* out = (float*)d_out;

  __hip_bfloat16* phi = (__hip_bfloat16*)d_ws;            // 1024*2304 bf16 = 4.5 MiB
  __hip_bfloat16* W   = phi + (size_t)B_SZ * KTOT;        // 256*2304 bf16 = 1.125 MiB

  kan_prep<<<(B_SZ * IN_F + OUT_F * IN_F) / 256, 256, 0, stream>>>(
      x, grid, coeff, bw, sw, phi, W);
  kan_gemm<<<(B_SZ / 32) * (OUT_F / 32), 512, 0, stream>>>(phi, W, out);
}